// Round 6
// baseline (49029.308 us; speedup 1.0000x reference)
//
#include <hip/hip_runtime.h>
#include <string.h>

// Quantum classifier fwd: 14 qubits, batch 4096, 6 StronglyEntanglingLayers.
// Round 6: inline-asm v_pk_fma_f16 complex math (op_sel half-swap + neg_lo
// conjugate fold; 2 instr per complex mul-acc), gates as u32 {re,im} in SGPRs,
// f16 state in exactly 64 KiB LDS (enc/reduction reuse the state buffer),
// GF(2) relabeling tables host-built, rank-5 conflict-free scatter writes.

#define NQ      14
#define NLAYERS 6
#define NSTATE  16384
#define BLOCK   1024

typedef unsigned u32;
typedef _Float16 h2 __attribute__((ext_vector_type(2)));

struct AllTables {
  u32 swlo[24][4];      // per-pass role low-masks (slot-indexed)
  u32 wA[23][10];       // write map: columns for thread bits
  u32 wB[23][16];       // write map: top-part images (gamma-indexed)
  u32 a0[10], b0[16];   // init scatter (= W_0)
  u32 erlo[2], erhi[2]; // expectation sign rows in final layout
  int check;
  int minr;
};

// ---------------- host-side GF(2) machinery ----------------
namespace qct {

struct GF2 { unsigned short r[NQ]; };
static GF2 gf2_id(){ GF2 m{}; for(int i=0;i<NQ;++i) m.r[i]=(unsigned short)(1u<<i); return m; }
static GF2 gf2_mul(const GF2& A, const GF2& B){
  GF2 C{};
  for(int i=0;i<NQ;++i){ u32 v=0; for(int k=0;k<NQ;++k) if((A.r[i]>>k)&1) v^=B.r[k]; C.r[i]=(unsigned short)v; }
  return C;
}
static GF2 cnotF(int c, int t){
  GF2 F=gf2_id();
  F.r[13-t]=(unsigned short)((1u<<(13-t))|(1u<<(13-c)));
  return F;
}

struct Lin { u32 c[14]; };
static u32 lapply(const Lin& L, u32 x){ u32 r=0; for(int j=0;j<14;++j) if((x>>j)&1u) r^=L.c[j]; return r; }
static Lin lcompose(const Lin& A, const Lin& B){ Lin R{}; for(int j=0;j<14;++j) R.c[j]=lapply(A,B.c[j]); return R; }
static Lin lident(){ Lin L{}; for(int j=0;j<14;++j) L.c[j]=1u<<j; return L; }
static Lin linverse(const Lin& L){
  u32 rows[14]={0}, inv[14]={0};
  for(int i=0;i<14;++i){ u32 r=0; for(int j=0;j<14;++j) r|=((L.c[j]>>i)&1u)<<j; rows[i]=r; inv[i]=1u<<i; }
  for(int col=0; col<14; ++col){
    int piv=-1;
    for(int i=col;i<14;++i) if((rows[i]>>col)&1u){piv=i;break;}
    if(piv<0) continue;
    u32 tr=rows[col]; rows[col]=rows[piv]; rows[piv]=tr;
    tr=inv[col]; inv[col]=inv[piv]; inv[piv]=tr;
    for(int i=0;i<14;++i) if(i!=col && ((rows[i]>>col)&1u)){ rows[i]^=rows[col]; inv[i]^=inv[col]; }
  }
  Lin R{};
  for(int j=0;j<14;++j){ u32 cc=0; for(int i=0;i<14;++i) cc|=((inv[i]>>j)&1u)<<i; R.c[j]=cc; }
  return R;
}
static u32 roletrans(const Lin& invS, u32 rho){
  u32 r=0;
  for(int j=0;j<14;++j) r |= (u32)(__builtin_popcount(invS.c[j]&rho)&1) << j;
  return r;
}

struct Span14 { u32 E[14]; u32 EI[14]; };
static void span_init(Span14& S){ for(int i=0;i<14;++i){S.E[i]=0;S.EI[i]=0;} }
static int top14(u32 v){ for(int i=13;i>=0;--i) if((v>>i)&1u) return i; return -1; }
struct Red { u32 v; u32 img; };
static Red span_reduce(const Span14& S, u32 v){
  u32 img=0;
  while(v){
    int b=top14(v);
    if(!S.E[b]) break;
    v^=S.E[b]; img^=S.EI[b];
  }
  Red r; r.v=v; r.img=img; return r;
}
static bool span_add(Span14& S, u32 v, u32 img){
  Red r=span_reduce(S,v);
  if(!r.v) return false;
  int b=top14(r.v);
  S.E[b]=r.v; S.EI[b]=img^r.img;
  return true;
}
static bool span_has(const Span14& S, u32 v){ Red r=span_reduce(S,v); return r.v==0; }

struct WOut { Lin W; int rk; bool okbuild; };

// Build W with W(cin[i]) = cim[i]; criterion: lane bits 0..4 -> write-address
// low 5 bits (b32 banks), INCLUDING the role/SW term from `lo`, rank 5.
static WOut build_w(const u32* cin, const u32* cim, int nc, const u32* lo, u32 seed){
  WOut O{}; O.okbuild=true; O.rk=0;
  Span14 SI; span_init(SI);
  Span14 IM; span_init(IM);
  for(int i=0;i<nc;++i){
    if(!span_add(SI,cin[i],cim[i])) O.okbuild=false;
    if(!span_add(IM,cim[i],0))      O.okbuild=false;
  }
  u32 Bcol[4]={0,0,0,0};
  for(int i=0;i<4 && O.okbuild;++i){          // define W on e_{10+i}
    u32 x=1u<<(10+i);
    Red r=span_reduce(SI,x);
    if(r.v==0){ Bcol[i]=r.img; continue; }
    u32 img=0; bool found=false;
    for(int uu=0; uu<14 && !found; ++uu){
      int u=13-(int)(((u32)uu+(seed%14u))%14u);
      u32 cand=1u<<u;
      if(!span_has(IM,cand)){img=cand;found=true;}
    }
    if(!found){O.okbuild=false;break;}
    span_add(SI,x,img); span_add(IM,img,0);
    Bcol[i]=img;
  }
  u32 A5[5]={0,0,0,0,0};
  for(int j=0;j<5 && O.okbuild;++j){          // criterion bits (banks: low 5)
    u32 X=0;
    for(int i=0;i<4;++i) if((lo[i]>>j)&1u) X^=Bcol[i];
    u32 x=1u<<j;
    Red r=span_reduce(SI,x);
    if(r.v==0){ A5[j]=r.img^X; continue; }
    u32 img=0; bool found=false;
    for(u32 fm=0; fm<512u && !found; ++fm){
      u32 cand=(x^X)^((fm^(seed&511u))<<5);   // fixes only touch bits >=5
      if(cand && !span_has(IM,cand)){img=cand;found=true;}
    }
    if(!found){O.okbuild=false;break;}
    span_add(SI,x,img); span_add(IM,img,0);
    A5[j]=img^X;
  }
  for(int j=5;j<10 && O.okbuild;++j){         // completion
    u32 x=1u<<j;
    if(span_has(SI,x)) continue;
    u32 img=0; bool found=false;
    for(u32 fm=0; fm<4096u && !found; ++fm){
      u32 cand=x^fm;
      if(cand && !span_has(IM,cand)){img=cand;found=true;}
    }
    if(!found){O.okbuild=false;break;}
    span_add(SI,x,img); span_add(IM,img,0);
  }
  if(O.okbuild){
    for(int j=0;j<14;++j){
      Red r=span_reduce(SI,1u<<j);
      if(r.v){O.okbuild=false;break;}
      O.W.c[j]=r.img;
    }
  }
  {
    u32 rr2[5]={A5[0]&31u,A5[1]&31u,A5[2]&31u,A5[3]&31u,A5[4]&31u};
    int rk=0;
    for(int c2=4;c2>=0;--c2){
      int p=-1;
      for(int i2=0;i2<5;++i2) if((rr2[i2]>>c2)&1u){p=i2;break;}
      if(p<0) continue;
      ++rk;
      u32 pv=rr2[p]; rr2[p]=0;
      for(int i2=0;i2<5;++i2) if((rr2[i2]>>c2)&1u) rr2[i2]^=pv;
    }
    O.rk=rk;
  }
  return O;
}

static AllTables make_all(){
  AllTables T; memset(&T, 0, sizeof(T));
  T.check=1; T.minr=5;
  u32 MU[84]={0}, RHO[84]={0}; u32 er0=0, er1=0;
  {
    GF2 G=gf2_id(), H=gf2_id();
    for(int l=0;l<NLAYERS;++l){
      for(int q=0;q<NQ;++q){
        int idx=l*NQ+q, bit=13-q;
        u32 m=0;
        for(int r=0;r<NQ;++r) m |= ((u32)((H.r[r]>>bit)&1u))<<r;
        MU[idx]=m; RHO[idx]=G.r[bit];
        if(!(__builtin_popcount(m & (u32)G.r[bit])&1)) T.check=0;
      }
      int rr=(l%(NQ-1))+1;
      GF2 C=gf2_id(), Ci=gf2_id();
      for(int q=0;q<NQ;++q){
        GF2 F=cnotF(q,(q+rr)%NQ);
        C=gf2_mul(C,F); Ci=gf2_mul(F,Ci);
      }
      G=gf2_mul(Ci,G); H=gf2_mul(H,C);
    }
    er0=G.r[13]; er1=G.r[12];
  }
  Lin S=lident();
  u32 lo_prev[4]={0,0,0,0};
  for(int b=0;b<24;++b){
    const int l=b>>2, g=b&3;
    const int ng=(g<3)?4:2, q0=(g<3)?4*g:12;
    u32 cin[4]={0,0,0,0}, cim[4]={0,0,0,0}; int nc=0;
    for(int i=0;i<ng;++i){
      cin[nc]=lapply(S,MU[l*NQ+q0+i]);
      cim[nc]=(ng==4)?(1u<<(10+i)):(1u<<(12+i));
      ++nc;
    }
    if(ng==2){
      Lin invS=linverse(S);
      u32 rp0=roletrans(invS,RHO[l*NQ+12]);
      u32 rp1=roletrans(invS,RHO[l*NQ+13]);
      int got=0;
      for(u32 cs=1; cs<16384u && got<2; ++cs){
        u32 v=(cs*2654435761u)&16383u;
        if(!v) continue;
        if(__builtin_popcount(v&rp0)&1) continue;
        if(__builtin_popcount(v&rp1)&1) continue;
        Span14 tmp; span_init(tmp);
        bool ind=true;
        for(int i=0;i<nc;++i) if(!span_add(tmp,cin[i],0)) ind=false;
        if(ind && span_add(tmp,v,0)){ cin[nc]=v; cim[nc]=1u<<(10+got); ++nc; ++got; }
      }
      if(got<2) T.check=0;
    }
    WOut best; memset(&best,0,sizeof(best)); bool haveBest=false;
    for(u32 sd=0; sd<2048; ++sd){
      WOut w=build_w(cin,cim,nc,lo_prev, sd*2654435761u + (u32)b*40503u + 1u);
      if(!haveBest || (w.okbuild && !best.okbuild) ||
         (w.okbuild==best.okbuild && w.rk>best.rk)){ best=w; haveBest=true; }
      if(best.okbuild && best.rk==5) break;
    }
    if(!best.okbuild) T.check=0;
    if(best.rk<T.minr) T.minr=best.rk;
    if(b==0){
      for(int j=0;j<10;++j) T.a0[j]=best.W.c[j];
      for(int gm=0;gm<16;++gm){ u32 x=0; for(int i=0;i<4;++i) if((gm>>i)&1) x^=best.W.c[10+i]; T.b0[gm]=x; }
    } else {
      for(int j=0;j<10;++j) T.wA[b-1][j]=best.W.c[j];
      for(int gm=0;gm<16;++gm){ u32 x=0; for(int i=0;i<4;++i) if((gm>>i)&1) x^=best.W.c[10+i]; T.wB[b-1][gm]=x; }
    }
    S=lcompose(best.W,S);
    Lin invS2=linverse(S);
    for(int i=0;i<4;++i) T.swlo[b][i]=0;
    for(int i=0;i<ng;++i){
      int gi=l*NQ+q0+i;
      u32 rp=roletrans(invS2,RHO[gi]);
      int slot=(ng==4)?i:(2+i);
      T.swlo[b][slot]=rp&0x3FFu;
      if(((rp>>10)&15u) != (1u<<slot)) T.check=0;
      if(lapply(S,MU[gi]) != (1u<<(10+slot))) T.check=0;
    }
    for(int i=0;i<4;++i) lo_prev[i]=T.swlo[b][i];
  }
  Lin invF=linverse(S);
  u32 e0=roletrans(invF,er0), e1=roletrans(invF,er1);
  T.erlo[0]=e0&0x3FFu; T.erhi[0]=(e0>>10)&15u;
  T.erlo[1]=e1&0x3FFu; T.erhi[1]=(e1>>10)&15u;
  return T;
}

} // namespace qct

// ---------------- device code ----------------
// Packed-complex f16 arithmetic via raw VOP3P. Amplitude = {re, im} in one
// VGPR; gate element g = {re, im} in one SGPR. A complex mul-acc is exactly
// two v_pk_fma_f16: op_sel swaps halves of the sources, neg_lo applies the
// -ui*pi sign. No swizzles, no gate pre-expansion.

__device__ __forceinline__ h2 cmul(u32 g, h2 p){   // o = u * p (2 instr)
  h2 o;
  asm("v_pk_mul_f16 %0, %1, %2 op_sel:[0,0] op_sel_hi:[0,1]\n\t"
      "v_pk_fma_f16 %0, %1, %2, %0 op_sel:[1,1,0] op_sel_hi:[1,0,1] neg_lo:[1,0,0]"
      : "=&v"(o) : "s"(g), "v"(p));
  return o;
}
__device__ __forceinline__ void cfma(u32 g, h2 p, h2& acc){  // acc += u*p
  asm("v_pk_fma_f16 %0, %1, %2, %0 op_sel:[0,0,0] op_sel_hi:[0,1,1]\n\t"
      "v_pk_fma_f16 %0, %1, %2, %0 op_sel:[1,1,0] op_sel_hi:[1,0,1] neg_lo:[1,0,0]"
      : "+v"(acc) : "s"(g), "v"(p));
}
// SU(2) on a pair: 8 packed instrs
__device__ __forceinline__ void su2a(uint4 G, h2& p, h2& q){
  h2 o0 = cmul(G.x, p); cfma(G.y, q, o0);
  h2 o1 = cmul(G.z, p); cfma(G.w, q, o1);
  p = o0; q = o1;
}

static __device__ __forceinline__ u32 packh(float re, float im){
  h2 v; v.x = (_Float16)re; v.y = (_Float16)im;
  u32 r; __builtin_memcpy(&r, &v, 4); return r;
}

// pre-kernel: Rot matrices -> u32-packed {re,im} per element (4 u32/gate)
__global__ void gate_kernel(const float* __restrict__ w, u32* __restrict__ gws){
  const int t = threadIdx.x;
  if (t < NLAYERS*NQ) {
    const float phi=w[3*t+0], th=w[3*t+1], om=w[3*t+2];
    const float ct=cosf(0.5f*th), stt=sinf(0.5f*th);
    const float aa=0.5f*(phi+om), bb=0.5f*(phi-om);
    const float ca=cosf(aa), sa=sinf(aa);
    const float cb=cosf(bb), sb=sinf(bb);
    u32* o = gws + 4*t;
    o[0] = packh( ca*ct, -sa*ct);    // u00
    o[1] = packh(-cb*stt, -sb*stt);  // u01
    o[2] = packh( cb*stt, -sb*stt);  // u10
    o[3] = packh( ca*ct,  sa*ct);    // u11
  }
}

extern "C" __global__ void __launch_bounds__(BLOCK, 8)
qc_kernel(const float* __restrict__ x, const u32* __restrict__ gws,
          float* __restrict__ out, const AllTables T){
  extern __shared__ u32 ldsRaw[];                 // exactly 64 KiB
  h2*    st   = reinterpret_cast<h2*>(ldsRaw);    // 16384 amplitudes
  float* encf = reinterpret_cast<float*>(ldsRaw); // init scratch (reused)
  float* red  = reinterpret_cast<float*>(ldsRaw); // epilogue scratch (reused)

  const unsigned t = threadIdx.x;
  const unsigned s = blockIdx.x;

  // --- encoding angles into LDS scratch (overlaps state; ordered by barriers)
  if (t < NQ) {
    const float h = x[s*NQ + t] * 1.57079632679489662f;
    encf[2*t]   = cosf(h);
    encf[2*t+1] = sinf(h);
  }
  __syncthreads();

  // --- init: read enc -> registers, barrier, then scattered product-state stores
  {
    float pr = 1.0f;
    #pragma unroll
    for (int b = 0; b < 10; ++b) pr *= encf[2*(13-b) + ((t>>b)&1u)];
    float e[8];
    #pragma unroll
    for (int j = 0; j < 8; ++j) e[j] = encf[j];
    __syncthreads();           // all reads done before stores overwrite scratch
    u32 a0 = 0;
    #pragma unroll
    for (int j = 0; j < 10; ++j) a0 ^= (0u-((t>>j)&1u)) & T.a0[j];
    #pragma unroll
    for (int i = 0; i < 16; ++i) {
      float vv = pr;
      #pragma unroll
      for (int bq = 0; bq < 4; ++bq) vv *= e[2*(3-bq) + ((i>>bq)&1)];
      h2 val; val.x = (_Float16)vv; val.y = (_Float16)0.0f;
      st[a0 ^ T.b0[i]] = val;
    }
  }
  __syncthreads();

  u32 SW = 0;
  h2 v[16];

  // --- passes 0..22 (with scatter stores) ---
  #pragma unroll 1
  for (int k = 0; k < 23; ++k) {
    const int l = k>>2, g = k&3;
    const bool four = (g < 3);
    const int q0 = four ? 4*g : 12;
    const uint4* gq = reinterpret_cast<const uint4*>(gws) + (l*NQ + q0);

    const u32 s0 = (u32)(__popc(t & T.swlo[k][0]) & 1);
    const u32 s1 = (u32)(__popc(t & T.swlo[k][1]) & 1);
    const u32 s2 = (u32)(__popc(t & T.swlo[k][2]) & 1);
    const u32 s3 = (u32)(__popc(t & T.swlo[k][3]) & 1);
    SW = s0 | (s1<<1) | (s2<<2) | (s3<<3);

    const u32 rb = t ^ (SW<<10);
    #pragma unroll
    for (int c = 0; c < 16; ++c) v[c] = st[rb ^ ((u32)c<<10)];

    if (four) {
      #pragma unroll
      for (int i = 0; i < 4; ++i) {
        const uint4 G = gq[i];
        #pragma unroll
        for (int c = 0; c < 16; ++c)
          if (!(c & (1<<i)))
            su2a(G, v[c], v[c | (1<<i)]);
      }
    } else {
      const uint4 G0 = gq[0], G1 = gq[1];
      #pragma unroll
      for (int c = 0; c < 16; ++c) if (!(c & 4)) su2a(G0, v[c], v[c|4]);
      #pragma unroll
      for (int c = 0; c < 16; ++c) if (!(c & 8)) su2a(G1, v[c], v[c|8]);
    }

    __syncthreads();   // all reads done before any scatter lands

    u32 ab = 0;
    #pragma unroll
    for (int j = 0; j < 10; ++j) ab ^= (0u-((t>>j)&1u)) & T.wA[k][j];
    ab ^= (0u-s0) & T.wB[k][1];
    ab ^= (0u-s1) & T.wB[k][2];
    ab ^= (0u-s2) & T.wB[k][4];
    ab ^= (0u-s3) & T.wB[k][8];
    #pragma unroll
    for (int c = 0; c < 16; ++c) st[ab ^ T.wB[k][c]] = v[c];

    __syncthreads();   // scatter complete before next pass reads
  }

  // --- pass 23 (2-gate) fused with expectation, no store ---
  {
    const int k = 23;
    const uint4* gq = reinterpret_cast<const uint4*>(gws) + (5*NQ + 12);
    const u32 s2 = (u32)(__popc(t & T.swlo[k][2]) & 1);
    const u32 s3 = (u32)(__popc(t & T.swlo[k][3]) & 1);
    SW = (s2<<2) | (s3<<3);
    const u32 rb = t ^ (SW<<10);
    #pragma unroll
    for (int c = 0; c < 16; ++c) v[c] = st[rb ^ ((u32)c<<10)];
    const uint4 G0 = gq[0], G1 = gq[1];
    #pragma unroll
    for (int c = 0; c < 16; ++c) if (!(c & 4)) su2a(G0, v[c], v[c|4]);
    #pragma unroll
    for (int c = 0; c < 16; ++c) if (!(c & 8)) su2a(G1, v[c], v[c|8]);
  }

  float z0 = 0.0f, z1 = 0.0f;
  #pragma unroll
  for (int c = 0; c < 16; ++c) {
    const float re = (float)v[c].x, im = (float)v[c].y;
    const float pr = re*re + im*im;
    const bool sg0 = (__popc((u32)c & T.erhi[0]) & 1) != 0;
    const bool sg1 = (__popc((u32)c & T.erhi[1]) & 1) != 0;
    z0 += sg0 ? -pr : pr;
    z1 += sg1 ? -pr : pr;
  }
  {
    const u32 f0 = (u32)((__popc(t & T.erlo[0]) ^ __popc(SW & T.erhi[0])) & 1);
    const u32 f1 = (u32)((__popc(t & T.erlo[1]) ^ __popc(SW & T.erhi[1])) & 1);
    if (f0) z0 = -z0;
    if (f1) z1 = -z1;
  }

  #pragma unroll
  for (int off = 32; off > 0; off >>= 1) {
    z0 += __shfl_down(z0, off, 64);
    z1 += __shfl_down(z1, off, 64);
  }
  __syncthreads();                         // state reads finished; reuse LDS
  if ((t & 63u) == 0u) { red[(t>>6)*2] = z0; red[(t>>6)*2+1] = z1; }
  __syncthreads();
  if (t == 0) {
    float a0 = 0.0f, a1 = 0.0f;
    #pragma unroll
    for (int kk = 0; kk < 16; ++kk) { a0 += red[2*kk]; a1 += red[2*kk+1]; }
    out[2*s]   = a0;
    out[2*s+1] = a1;
  }
}

extern "C" void kernel_launch(void* const* d_in, const int* in_sizes, int n_in,
                              void* d_out, int out_size, void* d_ws, size_t ws_size,
                              hipStream_t stream) {
  const float* x = (const float*)d_in[0];   // (4096, 14) f32
  const float* w = (const float*)d_in[1];   // (6, 14, 3) f32
  float* out = (float*)d_out;               // (4096, 2) f32
  u32* gws = (u32*)d_ws;                    // 84 * 4 u32
  const int B = in_sizes[0] / NQ;

  const AllTables T = qct::make_all();      // deterministic host work

  gate_kernel<<<1, 128, 0, stream>>>(w, gws);

  const size_t lds_bytes = (size_t)NSTATE * sizeof(u32);   // 65536 B exactly
  (void)hipFuncSetAttribute(reinterpret_cast<const void*>(qc_kernel),
                            hipFuncAttributeMaxDynamicSharedMemorySize,
                            (int)lds_bytes);
  qc_kernel<<<B, BLOCK, lds_bytes, stream>>>(x, gws, out, T);
}

// Round 8
// 677.175 us; speedup vs baseline: 72.4027x; 72.4027x over previous
//
#include <hip/hip_runtime.h>
#include <string.h>

// Quantum classifier fwd: 14 qubits, batch 4096, 6 StronglyEntanglingLayers.
// Round 8 (= Round 7 + cvt_pkrtz type fix). MFMA formulation: each 4-qubit
// fused pass = 16x16 complex unitary on 1024 columns -> two
// v_mfma_f32_16x16x32_f16 (re/im A-planes, f32 accum) per 16-col tile;
// B-frag reg r == one packed {re,im} f16 amp (u32) straight from LDS.
// Gate A-fragments prebuilt per-lane by the pre-kernel (48 KB in d_ws).
// GF(2) relabeling: canonical gamma bits at addr {12,13,4,5}; deterministic
// table builder (no seed search -> no host-time leak, the R5/R6 regression).

#define NQ     14
#define NL     6
#define NSTATE 16384
#define BLOCK  1024
#define NPASS  24

typedef unsigned u32;
typedef _Float16 h8  __attribute__((ext_vector_type(8)));
typedef _Float16 h2v __attribute__((ext_vector_type(2)));
typedef __fp16   p2v __attribute__((ext_vector_type(2)));
typedef float    f4  __attribute__((ext_vector_type(4)));

struct AllTables {
  u32 rhoc[NPASS][4];   // pass roles compressed to col-index space (10-bit)
  u32 wCol[NPASS-1][10];// write map: images of col-index bits (14-bit addrs)
  u32 wGam[NPASS-1][4]; // write map: images of gamma bits
  u32 a0[10], b0[16];   // init scatter (= W_0 over original basis)
  u32 erlo[2], erhi[2]; // expectation sign rows (col-index / gamma spaces)
  int check;
};

// gamma bit i lives at address bit GB[i]; col-index bit j at CB[j]
static const int GBh[4]  = {12,13,4,5};
static const int CBh[10] = {0,1,2,3,6,7,8,9,10,11};

// ---------------- host-side GF(2) machinery (proven in R4-R6) ----------------
namespace qct {

struct GF2 { unsigned short r[NQ]; };
static GF2 gf2_id(){ GF2 m{}; for(int i=0;i<NQ;++i) m.r[i]=(unsigned short)(1u<<i); return m; }
static GF2 gf2_mul(const GF2& A, const GF2& B){
  GF2 C{};
  for(int i=0;i<NQ;++i){ u32 v=0; for(int k=0;k<NQ;++k) if((A.r[i]>>k)&1) v^=B.r[k]; C.r[i]=(unsigned short)v; }
  return C;
}
static GF2 cnotF(int c, int t){
  GF2 F=gf2_id();
  F.r[13-t]=(unsigned short)((1u<<(13-t))|(1u<<(13-c)));
  return F;
}

struct Lin { u32 c[14]; };
static u32 lapply(const Lin& L, u32 x){ u32 r=0; for(int j=0;j<14;++j) if((x>>j)&1u) r^=L.c[j]; return r; }
static Lin lcompose(const Lin& A, const Lin& B){ Lin R{}; for(int j=0;j<14;++j) R.c[j]=lapply(A,B.c[j]); return R; }
static Lin lident(){ Lin L{}; for(int j=0;j<14;++j) L.c[j]=1u<<j; return L; }
static Lin linverse(const Lin& L){
  u32 rows[14]={0}, inv[14]={0};
  for(int i=0;i<14;++i){ u32 r=0; for(int j=0;j<14;++j) r|=((L.c[j]>>i)&1u)<<j; rows[i]=r; inv[i]=1u<<i; }
  for(int col=0; col<14; ++col){
    int piv=-1;
    for(int i=col;i<14;++i) if((rows[i]>>col)&1u){piv=i;break;}
    if(piv<0) continue;
    u32 tr=rows[col]; rows[col]=rows[piv]; rows[piv]=tr;
    tr=inv[col]; inv[col]=inv[piv]; inv[piv]=tr;
    for(int i=0;i<14;++i) if(i!=col && ((rows[i]>>col)&1u)){ rows[i]^=rows[col]; inv[i]^=inv[col]; }
  }
  Lin R{};
  for(int j=0;j<14;++j){ u32 cc=0; for(int i=0;i<14;++i) cc|=((inv[i]>>j)&1u)<<i; R.c[j]=cc; }
  return R;
}
static u32 roletrans(const Lin& invS, u32 rho){
  u32 r=0;
  for(int j=0;j<14;++j) r |= (u32)(__builtin_popcount(invS.c[j]&rho)&1) << j;
  return r;
}

struct Span14 { u32 E[14]; u32 EI[14]; };
static void span_init(Span14& S){ for(int i=0;i<14;++i){S.E[i]=0;S.EI[i]=0;} }
static int top14(u32 v){ for(int i=13;i>=0;--i) if((v>>i)&1u) return i; return -1; }
struct Red { u32 v; u32 img; };
static Red span_reduce(const Span14& S, u32 v){
  u32 img=0;
  while(v){
    int b=top14(v);
    if(!S.E[b]) break;
    v^=S.E[b]; img^=S.EI[b];
  }
  Red r; r.v=v; r.img=img; return r;
}
static bool span_add(Span14& S, u32 v, u32 img){
  Red r=span_reduce(S,v);
  if(!r.v) return false;
  int b=top14(r.v);
  S.E[b]=r.v; S.EI[b]=img^r.img;
  return true;
}
static bool span_has(const Span14& S, u32 v){ Red r=span_reduce(S,v); return r.v==0; }

static u32 cmprs_col(u32 v){ u32 r=0; for(int j=0;j<10;++j) r |= ((v>>CBh[j])&1u)<<j; return r; }
static u32 cmprs_gam(u32 v){ u32 r=0; for(int i=0;i<4;++i)  r |= ((v>>GBh[i])&1u)<<i; return r; }

static AllTables make_all(){
  AllTables T; memset(&T,0,sizeof(T)); T.check=1;
  u32 MU[84]={0}, RHO[84]={0}; u32 er0=0, er1=0;
  {
    GF2 G=gf2_id(), H=gf2_id();
    for(int l=0;l<NL;++l){
      for(int q=0;q<NQ;++q){
        int idx=l*NQ+q, bit=13-q;
        u32 m=0;
        for(int r=0;r<NQ;++r) m |= ((u32)((H.r[r]>>bit)&1u))<<r;
        MU[idx]=m; RHO[idx]=G.r[bit];
        if(!(__builtin_popcount(m & (u32)G.r[bit])&1)) T.check=0;
      }
      int rr=(l%(NQ-1))+1;
      GF2 C=gf2_id(), Ci=gf2_id();
      for(int q=0;q<NQ;++q){
        GF2 F=cnotF(q,(q+rr)%NQ);
        C=gf2_mul(C,F); Ci=gf2_mul(F,Ci);
      }
      G=gf2_mul(Ci,G); H=gf2_mul(H,C);
    }
    er0=G.r[13]; er1=G.r[12];
  }
  Lin S=lident();
  u32 lo_prev[4]={0,0,0,0};
  for(int b=0;b<NPASS;++b){
    const int layer=b>>2, g=b&3;
    const int ng=(g<3)?4:2, q0=(g<3)?4*g:12;
    u32 cin[4]={0,0,0,0};
    for(int i=0;i<ng;++i) cin[i]=lapply(S,MU[layer*NQ+q0+i]);
    if(ng==2){
      // free directions (slots 2,3): orthogonal to both real roles, independent
      Lin invS=linverse(S);
      u32 rp0=roletrans(invS,RHO[layer*NQ+12]);
      u32 rp1=roletrans(invS,RHO[layer*NQ+13]);
      int got=0;
      for(u32 cs=1; cs<16384u && got<2; ++cs){
        u32 v=(cs*2654435761u)&16383u;
        if(!v) continue;
        if(__builtin_popcount(v&rp0)&1) continue;
        if(__builtin_popcount(v&rp1)&1) continue;
        Span14 tmp; span_init(tmp); bool ind=true;
        for(int i=0;i<2+got;++i) if(!span_add(tmp,cin[i],0)) ind=false;
        if(ind){ cin[2+got]=v; ++got; }
      }
      if(got<2) T.check=0;
    }
    // ---- deterministic W build (no seed search) ----
    Span14 SI; span_init(SI);
    Span14 IM; span_init(IM);
    bool ok=true;
    for(int i=0;i<4;++i){
      if(!span_add(SI,cin[i],1u<<GBh[i])) ok=false;
      if(!span_add(IM,1u<<GBh[i],0))      ok=false;
    }
    u32 wg[4]={0,0,0,0};
    for(int i=0;i<4 && ok;++i){            // define W on gamma domain bits
      u32 d=1u<<GBh[i];
      Red rr=span_reduce(SI,d);
      if(rr.v==0){ wg[i]=rr.img; continue; }
      u32 img=0; bool f=false;
      for(u32 fm=0; fm<16384u && !f; ++fm){ u32 cand=d^fm; if(cand && !span_has(IM,cand)){img=cand;f=true;} }
      if(!f){ok=false;break;}
      span_add(SI,d,img); span_add(IM,img,0); wg[i]=img;
    }
    u32 X[4]={0,0,0,0};
    for(int j=0;j<4;++j){ u32 xx=0; for(int i=0;i<4;++i) if((lo_prev[i]>>j)&1u) xx^=wg[i]; X[j]=xx; }
    for(int j=0;j<4 && ok;++j){            // n-bits: shape write banks
      u32 d=1u<<CBh[j];
      if(span_has(SI,d)) continue;
      u32 pref=((1u<<j)^X[j])&16383u;
      u32 img=0; bool f=false;
      for(u32 fm=0; fm<512u && !f; ++fm){ u32 cand=(pref^(fm<<5))&16383u; if(cand && !span_has(IM,cand)){img=cand;f=true;} }
      for(u32 fm=0; fm<16384u && !f; ++fm){ u32 cand=(pref^fm)&16383u; if(cand && !span_has(IM,cand)){img=cand;f=true;} }
      if(!f){ok=false;break;}
      span_add(SI,d,img); span_add(IM,img,0);
    }
    for(int j=4;j<10 && ok;++j){           // completion on remaining col bits
      u32 d=1u<<CBh[j];
      if(span_has(SI,d)) continue;
      u32 img=0; bool f=false;
      for(u32 fm=0; fm<16384u && !f; ++fm){ u32 cand=d^fm; if(cand && !span_has(IM,cand)){img=cand;f=true;} }
      if(!f){ok=false;break;}
      span_add(SI,d,img); span_add(IM,img,0);
    }
    Lin W=lident();
    if(ok){
      for(int jb=0;jb<14;++jb){
        Red rr=span_reduce(SI,1u<<jb);
        if(rr.v){ok=false;break;}
        W.c[jb]=rr.img;
      }
    }
    if(!ok) T.check=0;
    if(b==0){
      for(int j=0;j<10;++j) T.a0[j]=W.c[j];
      for(int gm=0;gm<16;++gm){ u32 xx=0; for(int i=0;i<4;++i) if((gm>>i)&1) xx^=W.c[10+i]; T.b0[gm]=xx; }
    } else {
      for(int j=0;j<10;++j) T.wCol[b-1][j]=W.c[CBh[j]];
      for(int i=0;i<4;++i)  T.wGam[b-1][i]=W.c[GBh[i]];
    }
    S=lcompose(W,S);
    Lin invS2=linverse(S);
    for(int i=0;i<4;++i) T.rhoc[b][i]=0;
    for(int i=0;i<ng;++i){
      u32 rp=roletrans(invS2,RHO[layer*NQ+q0+i]);
      for(int ii=0;ii<4;++ii){
        u32 bit=(rp>>GBh[ii])&1u;
        if(bit != (u32)((ii==i)?1:0)) T.check=0;            // canonical role
      }
      if(lapply(S,MU[layer*NQ+q0+i]) != (1u<<GBh[i])) T.check=0; // canonical mask
      T.rhoc[b][i]=cmprs_col(rp);
    }
    for(int i=0;i<4;++i) lo_prev[i]=T.rhoc[b][i];
  }
  Lin invF=linverse(S);
  u32 e0=roletrans(invF,er0), e1=roletrans(invF,er1);
  T.erlo[0]=cmprs_col(e0); T.erhi[0]=cmprs_gam(e0);
  T.erlo[1]=cmprs_col(e1); T.erhi[1]=cmprs_gam(e1);
  return T;
}

} // namespace qct

// ---------------- device code ----------------

// pre-kernel: build per-lane MFMA A-fragments for all 24 pass matrices.
// A_re[m][2g+0]=Re U[m,g], A_re[m][2g+1]=-Im U[m,g];
// A_im[m][2g+0]=Im U[m,g], A_im[m][2g+1]= Re U[m,g].
// Lane l holds A[m=l&15][k=(l>>4)*8 + e], reg r = halves {k=kb+2r, k=kb+2r+1}.
__global__ void gate_kernel(const float* __restrict__ wgt, u32* __restrict__ gA){
  __shared__ float us[84][8];
  const int t = threadIdx.x;
  if (t < 84) {
    const float phi=wgt[3*t+0], th=wgt[3*t+1], om=wgt[3*t+2];
    const float ct=cosf(0.5f*th), stt=sinf(0.5f*th);
    const float aa=0.5f*(phi+om), bb=0.5f*(phi-om);
    const float ca=cosf(aa), sa=sinf(aa);
    const float cb=cosf(bb), sb=sinf(bb);
    us[t][0]= ca*ct;  us[t][1]=-sa*ct;    // u00
    us[t][2]=-cb*stt; us[t][3]=-sb*stt;   // u01
    us[t][4]= cb*stt; us[t][5]=-sb*stt;   // u10
    us[t][6]= ca*ct;  us[t][7]= sa*ct;    // u11
  }
  __syncthreads();
  for (int task = t; task < NPASS*64; task += (int)blockDim.x) {
    const int p = task >> 6, l = task & 63;
    const int m = l & 15, gb = ((l>>4)&3)*4;
    const int layer = p>>2, g = p&3;
    const int ng = (g<3)?4:2, q0 = (g<3)?4*g:12;
    u32 rre[4], rim[4];
    for (int r = 0; r < 4; ++r) {
      const int gam = gb + r;
      float ure=1.f, uim=0.f; bool zero=false;
      for (int sl = 0; sl < 4; ++sl) {
        const int mb=(m>>sl)&1, cbit=(gam>>sl)&1;
        float fre, fim;
        if (sl < ng) {
          const float* u = us[layer*NQ + q0 + sl];
          fre = u[(mb*2+cbit)*2]; fim = u[(mb*2+cbit)*2+1];
        } else {
          if (mb != cbit) zero = true;
          fre = 1.f; fim = 0.f;
        }
        const float nre = ure*fre - uim*fim;
        const float nim = ure*fim + uim*fre;
        ure = nre; uim = nim;
      }
      if (zero) { ure = 0.f; uim = 0.f; }
      h2v a; a.x=(_Float16)ure;  a.y=(_Float16)(-uim);
      h2v b; b.x=(_Float16)uim;  b.y=(_Float16)ure;
      __builtin_memcpy(&rre[r], &a, 4);
      __builtin_memcpy(&rim[r], &b, 4);
    }
    u32* o0 = gA + ((size_t)(p*2+0)*64 + l)*4;
    u32* o1 = gA + ((size_t)(p*2+1)*64 + l)*4;
    o0[0]=rre[0]; o0[1]=rre[1]; o0[2]=rre[2]; o0[3]=rre[3];
    o1[0]=rim[0]; o1[1]=rim[1]; o1[2]=rim[2]; o1[3]=rim[3];
  }
}

extern "C" __global__ void __launch_bounds__(BLOCK, 8)
qc_kernel(const float* __restrict__ x, const uint4* __restrict__ gA,
          float* __restrict__ out, const AllTables T){
  extern __shared__ u32 lds[];                // 16384 u32 = 64 KiB (state)
  const u32 t = threadIdx.x;
  const u32 s = blockIdx.x;
  const u32 l = t & 63u, w = t >> 6;
  const u32 q = (l >> 4) & 3u, n = l & 15u;

  // --- encoding angles (LDS scratch overlaps state; barrier-ordered) ---
  float* encf = reinterpret_cast<float*>(lds);
  if (t < NQ) {
    const float h = x[s*NQ + t] * 1.57079632679489662f;
    encf[2*t]   = cosf(h);
    encf[2*t+1] = sinf(h);
  }
  __syncthreads();

  // --- init: product state scattered through W_0 ---
  {
    float pr = 1.0f;
    #pragma unroll
    for (int b = 0; b < 10; ++b) pr *= encf[2*(13-b) + ((t>>b)&1u)];
    float e[8];
    #pragma unroll
    for (int j = 0; j < 8; ++j) e[j] = encf[j];
    __syncthreads();
    u32 a0f = 0;
    #pragma unroll
    for (int j = 0; j < 10; ++j) a0f ^= (0u-((t>>j)&1u)) & T.a0[j];
    #pragma unroll
    for (int i = 0; i < 16; ++i) {
      float vv = pr;
      #pragma unroll
      for (int bq = 0; bq < 4; ++bq) vv *= e[2*(3-bq) + ((i>>bq)&1)];
      h2v hv; hv.x = (_Float16)vv; hv.y = (_Float16)0.0f;
      u32 av; __builtin_memcpy(&av, &hv, 4);
      lds[a0f ^ T.b0[i]] = av;
    }
  }
  __syncthreads();

  f4  cre[4], cim[4];
  u32 swt[4];

  #pragma unroll 1
  for (int k = 0; k < NPASS; ++k) {
    const uint4 ar4 = gA[(size_t)(k*2+0)*64 + l];
    const uint4 ai4 = gA[(size_t)(k*2+1)*64 + l];
    h8 aRe, aIm;
    __builtin_memcpy(&aRe, &ar4, 16);
    __builtin_memcpy(&aIm, &ai4, 16);
    const u32 r0 = T.rhoc[k][0], r1 = T.rhoc[k][1];
    const u32 r2 = T.rhoc[k][2], r3 = T.rhoc[k][3];

    // --- read + MFMA per 16-col tile ---
    #pragma unroll
    for (int jt = 0; jt < 4; ++jt) {
      const u32 ci = (w<<6) | ((u32)jt<<4) | n;               // col index
      const u32 sw = (u32)(__popc(ci&r0)&1) | ((u32)(__popc(ci&r1)&1)<<1)
                   | ((u32)(__popc(ci&r2)&1)<<2) | ((u32)(__popc(ci&r3)&1)<<3);
      swt[jt] = sw;
      const u32 gx  = (q<<2) ^ sw;
      const u32 gsw = ((gx&3u)<<12) | ((gx&12u)<<2);          // gamma scatter
      const u32 cp  = n | ((((w<<2)|(u32)jt))<<6);            // col scatter
      const u32 base = cp ^ gsw;
      const u32 b0v = lds[base];
      const u32 b1v = lds[base ^ (1u<<12)];
      const u32 b2v = lds[base ^ (2u<<12)];
      const u32 b3v = lds[base ^ (3u<<12)];
      uint4 bv; bv.x=b0v; bv.y=b1v; bv.z=b2v; bv.w=b3v;
      h8 bf; __builtin_memcpy(&bf, &bv, 16);
      const f4 z = {0.f, 0.f, 0.f, 0.f};
      cre[jt] = __builtin_amdgcn_mfma_f32_16x16x32_f16(aRe, bf, z, 0, 0, 0);
      cim[jt] = __builtin_amdgcn_mfma_f32_16x16x32_f16(aIm, bf, z, 0, 0, 0);
    }
    __syncthreads();   // all reads done before any scatter-write lands

    if (k < NPASS-1) {
      u32 nf = 0;
      #pragma unroll
      for (int j = 0; j < 4; ++j) nf ^= (0u-((n>>j)&1u)) & T.wCol[k][j];
      u32 wf = 0;
      #pragma unroll
      for (int j = 0; j < 4; ++j) wf ^= (0u-((w>>j)&1u)) & T.wCol[k][6+j];
      const u32 wgq = ((q&1u)?T.wGam[k][2]:0u) ^ ((q&2u)?T.wGam[k][3]:0u);
      const u32 baseW = nf ^ wf ^ wgq;
      #pragma unroll
      for (int jt = 0; jt < 4; ++jt) {
        const u32 sw = swt[jt];
        const u32 swf = ((sw&1u)?T.wGam[k][0]:0u) ^ ((sw&2u)?T.wGam[k][1]:0u)
                      ^ ((sw&4u)?T.wGam[k][2]:0u) ^ ((sw&8u)?T.wGam[k][3]:0u);
        const u32 tf = ((jt&1)?T.wCol[k][4]:0u) ^ ((jt&2)?T.wCol[k][5]:0u);
        const u32 ab = baseW ^ swf ^ tf;
        #pragma unroll
        for (int r = 0; r < 4; ++r) {
          const u32 gr = (((u32)r&1u)?T.wGam[k][0]:0u) ^ (((u32)r&2u)?T.wGam[k][1]:0u);
          p2v hv = __builtin_amdgcn_cvt_pkrtz(cre[jt][r], cim[jt][r]);
          u32 av; __builtin_memcpy(&av, &hv, 4);
          lds[ab ^ gr] = av;
        }
      }
      __syncthreads();  // scatter complete before next pass reads
    }
  }

  // --- expectation from final C-fragments (f32, never stored) ---
  float z0 = 0.f, z1 = 0.f;
  #pragma unroll
  for (int jt = 0; jt < 4; ++jt) {
    const u32 ci = (w<<6) | ((u32)jt<<4) | n;
    const u32 sw = swt[jt];
    const u32 t0 = (u32)((__popc(ci&T.erlo[0]) ^ __popc(sw&T.erhi[0]) ^ __popc((q<<2)&T.erhi[0])) & 1);
    const u32 t1 = (u32)((__popc(ci&T.erlo[1]) ^ __popc(sw&T.erhi[1]) ^ __popc((q<<2)&T.erhi[1])) & 1);
    #pragma unroll
    for (int r = 0; r < 4; ++r) {
      const u32 s0r = (u32)(__popc(T.erhi[0] & (u32)r) & 1);
      const u32 s1r = (u32)(__popc(T.erhi[1] & (u32)r) & 1);
      const float p = cre[jt][r]*cre[jt][r] + cim[jt][r]*cim[jt][r];
      z0 += ((t0^s0r) != 0u) ? -p : p;
      z1 += ((t1^s1r) != 0u) ? -p : p;
    }
  }
  #pragma unroll
  for (int off = 32; off > 0; off >>= 1) {
    z0 += __shfl_down(z0, off, 64);
    z1 += __shfl_down(z1, off, 64);
  }
  __syncthreads();                       // state reads finished; reuse LDS
  float* red = reinterpret_cast<float*>(lds);
  if ((t & 63u) == 0u) { red[(t>>6)*2] = z0; red[(t>>6)*2+1] = z1; }
  __syncthreads();
  if (t == 0) {
    float a0s = 0.f, a1s = 0.f;
    #pragma unroll
    for (int kk = 0; kk < 16; ++kk) { a0s += red[2*kk]; a1s += red[2*kk+1]; }
    out[2*s]   = a0s;
    out[2*s+1] = a1s;
  }
}

extern "C" void kernel_launch(void* const* d_in, const int* in_sizes, int n_in,
                              void* d_out, int out_size, void* d_ws, size_t ws_size,
                              hipStream_t stream) {
  const float* x = (const float*)d_in[0];   // (4096, 14) f32
  const float* w = (const float*)d_in[1];   // (6, 14, 3) f32
  float* out = (float*)d_out;               // (4096, 2) f32
  u32* gA = (u32*)d_ws;                     // 24*2*64*4 u32 = 48 KiB
  const int B = in_sizes[0] / NQ;

  const AllTables T = qct::make_all();      // deterministic, ~50 us, no search

  gate_kernel<<<1, BLOCK, 0, stream>>>(w, gA);

  const size_t lds_bytes = (size_t)NSTATE * sizeof(u32);   // 65536 B
  (void)hipFuncSetAttribute(reinterpret_cast<const void*>(qc_kernel),
                            hipFuncAttributeMaxDynamicSharedMemorySize,
                            (int)lds_bytes);
  qc_kernel<<<B, BLOCK, lds_bytes, stream>>>(x, (const uint4*)gA, out, T);
}

// Round 9
// 636.514 us; speedup vs baseline: 77.0279x; 1.0639x over previous
//
#include <hip/hip_runtime.h>
#include <string.h>

// Quantum classifier fwd: 14 qubits, batch 4096, 6 StronglyEntanglingLayers.
// Round 9: MFMA + role purge + b128 reads.
//  - W built with row constraints = pass roles -> roles become pure gamma bits
//    (sw == 0): no popc/swap logic in the kernel, static read addresses
//  - gamma low bits at addr {0,1}: one ds_read_b128 per 16-col tile
//  - C-fragments cvt_pkrtz'd to u32 BEFORE the barrier: 16 live regs, no spill
//  - writes 4xb32/tile through W; free rows chosen to spread bank bits 2..4

#define NQ     14
#define NL     6
#define NSTATE 16384
#define BLOCK  1024
#define NPASS  24

typedef unsigned u32;
typedef _Float16 h8  __attribute__((ext_vector_type(8)));
typedef _Float16 h2v __attribute__((ext_vector_type(2)));
typedef __fp16   p2v __attribute__((ext_vector_type(2)));
typedef float    f4  __attribute__((ext_vector_type(4)));

struct AllTables {
  u32 wC[NPASS-1][10];  // write map: images of col bits (ci bit j -> addr)
  u32 wG[NPASS-1][4];   // write map: images of gamma bits {0,1,12,13}
  u32 a0[10], b0[16];   // init scatter (= W_0 over original basis)
  u32 erlo[2], erhi[2]; // expectation sign rows (col / gamma spaces)
  int check;
};

// gamma bit i lives at address bit GB[i]; col bit j at addr bit 2+j
static const int GBh[4] = {0, 1, 12, 13};

// ---------------- host-side GF(2) machinery ----------------
namespace qct {

struct GF2 { unsigned short r[NQ]; };
static GF2 gf2_id(){ GF2 m{}; for(int i=0;i<NQ;++i) m.r[i]=(unsigned short)(1u<<i); return m; }
static GF2 gf2_mul(const GF2& A, const GF2& B){
  GF2 C{};
  for(int i=0;i<NQ;++i){ u32 v=0; for(int k=0;k<NQ;++k) if((A.r[i]>>k)&1) v^=B.r[k]; C.r[i]=(unsigned short)v; }
  return C;
}
static GF2 cnotF(int c, int t){
  GF2 F=gf2_id();
  F.r[13-t]=(unsigned short)((1u<<(13-t))|(1u<<(13-c)));
  return F;
}

struct Lin { u32 c[14]; };
static u32 lapply(const Lin& L, u32 x){ u32 r=0; for(int j=0;j<14;++j) if((x>>j)&1u) r^=L.c[j]; return r; }
static Lin lcompose(const Lin& A, const Lin& B){ Lin R{}; for(int j=0;j<14;++j) R.c[j]=lapply(A,B.c[j]); return R; }
static Lin lident(){ Lin L{}; for(int j=0;j<14;++j) L.c[j]=1u<<j; return L; }
static Lin linverse(const Lin& L){
  u32 rows[14]={0}, inv[14]={0};
  for(int i=0;i<14;++i){ u32 r=0; for(int j=0;j<14;++j) r|=((L.c[j]>>i)&1u)<<j; rows[i]=r; inv[i]=1u<<i; }
  for(int col=0; col<14; ++col){
    int piv=-1;
    for(int i=col;i<14;++i) if((rows[i]>>col)&1u){piv=i;break;}
    if(piv<0) continue;
    u32 tr=rows[col]; rows[col]=rows[piv]; rows[piv]=tr;
    tr=inv[col]; inv[col]=inv[piv]; inv[piv]=tr;
    for(int i=0;i<14;++i) if(i!=col && ((rows[i]>>col)&1u)){ rows[i]^=rows[col]; inv[i]^=inv[col]; }
  }
  Lin R{};
  for(int j=0;j<14;++j){ u32 cc=0; for(int i=0;i<14;++i) cc|=((inv[i]>>j)&1u)<<i; R.c[j]=cc; }
  return R;
}
static u32 roletrans(const Lin& invS, u32 rho){
  u32 r=0;
  for(int j=0;j<14;++j) r |= (u32)(__builtin_popcount(invS.c[j]&rho)&1) << j;
  return r;
}

struct Span14 { u32 E[14]; u32 EI[14]; };
static void span_init(Span14& S){ for(int i=0;i<14;++i){S.E[i]=0;S.EI[i]=0;} }
static int top14(u32 v){ for(int i=13;i>=0;--i) if((v>>i)&1u) return i; return -1; }
struct Red { u32 v; u32 img; };
static Red span_reduce(const Span14& S, u32 v){
  u32 img=0;
  while(v){
    int b=top14(v);
    if(!S.E[b]) break;
    v^=S.E[b]; img^=S.EI[b];
  }
  Red r; r.v=v; r.img=img; return r;
}
static bool span_add(Span14& S, u32 v, u32 img){
  Red r=span_reduce(S,v);
  if(!r.v) return false;
  int b=top14(r.v);
  S.E[b]=r.v; S.EI[b]=img^r.img;
  return true;
}

// x with <x, cin[j]> = (tgt>>j)&1 for j<nc; 0xFFFFFFFF on failure
static u32 solve_dual(const u32* cin0, int nc, u32 tgt){
  u32 r[4]; u32 b[4]; int piv[4];
  for(int i=0;i<nc;++i){ r[i]=cin0[i]; b[i]=(tgt>>i)&1u; }
  for(int i=0;i<nc;++i){
    for(int k=0;k<i;++k) if((r[i]>>piv[k])&1u){ r[i]^=r[k]; b[i]^=b[k]; }
    piv[i]=-1;
    for(int p=0;p<14;++p) if((r[i]>>p)&1u){ piv[i]=p; break; }
    if(piv[i]<0) return 0xFFFFFFFFu;
  }
  for(int i=nc-1;i>=0;--i)
    for(int k=0;k<i;++k)
      if((r[k]>>piv[i])&1u){ r[k]^=r[i]; b[k]^=b[i]; }
  u32 x=0;
  for(int i=0;i<nc;++i) if(b[i]) x|=1u<<piv[i];
  return x;
}

// basis of {v : <v,cin_j>=0}; returns count (expect 14-nc)
static int nullspace(const u32* cin0, int nc, u32* basis){
  u32 r[4]; int piv[4]; int rank=0;
  for(int i=0;i<nc;++i){
    u32 row=cin0[i];
    for(int k=0;k<rank;++k) if((row>>piv[k])&1u) row^=r[k];
    if(!row) continue;
    int p=0; while(!((row>>p)&1u)) ++p;
    r[rank]=row; piv[rank]=p; ++rank;
  }
  for(int i=rank-1;i>=0;--i)
    for(int k=0;k<i;++k)
      if((r[k]>>piv[i])&1u) r[k]^=r[i];
  bool isp[14]; for(int i=0;i<14;++i) isp[i]=false;
  for(int i=0;i<rank;++i) isp[piv[i]]=true;
  int nb=0;
  for(int f=0;f<14;++f){
    if(isp[f]) continue;
    u32 v=1u<<f;
    for(int i=0;i<rank;++i) if((r[i]>>f)&1u) v|=1u<<piv[i];
    basis[nb++]=v;
  }
  return nb;
}

static AllTables make_all(){
  AllTables T; memset(&T,0,sizeof(T)); T.check=1;
  u32 MU[84]={0}, RHO[84]={0}; u32 er0=0, er1=0;
  {
    GF2 G=gf2_id(), H=gf2_id();
    for(int l=0;l<NL;++l){
      for(int q=0;q<NQ;++q){
        int idx=l*NQ+q, bit=13-q;
        u32 m=0;
        for(int r=0;r<NQ;++r) m |= ((u32)((H.r[r]>>bit)&1u))<<r;
        MU[idx]=m; RHO[idx]=G.r[bit];
        if(!(__builtin_popcount(m & (u32)G.r[bit])&1)) T.check=0;
      }
      int rr=(l%(NQ-1))+1;
      GF2 C=gf2_id(), Ci=gf2_id();
      for(int q=0;q<NQ;++q){
        GF2 F=cnotF(q,(q+rr)%NQ);
        C=gf2_mul(C,F); Ci=gf2_mul(F,Ci);
      }
      G=gf2_mul(Ci,G); H=gf2_mul(H,C);
    }
    er0=G.r[13]; er1=G.r[12];
  }
  Lin S=lident();
  for(int b=0;b<NPASS;++b){
    const int layer=b>>2, g=b&3;
    const int ng=(g<3)?4:2, q0=(g<3)?4*g:12;
    Lin invS=linverse(S);
    u32 cin[4]={0,0,0,0}, rc[4]={0,0,0,0};
    for(int i=0;i<ng;++i){
      cin[i]=lapply(S,MU[layer*NQ+q0+i]);
      rc[i]=roletrans(invS,RHO[layer*NQ+q0+i]);
    }
    if(ng==2){
      int got=0;
      for(u32 cs=1; cs<16384u && got<2; ++cs){
        u32 v=(cs*2654435761u)&16383u;
        if(!v) continue;
        if(__builtin_popcount(v&rc[0])&1) continue;
        if(__builtin_popcount(v&rc[1])&1) continue;
        Span14 tmp; span_init(tmp); bool ind=true;
        for(int i=0;i<2+got;++i) if(!span_add(tmp,cin[i],0)) ind=false;
        if(ind && span_add(tmp,v,0)){ cin[2+got]=v; ++got; }
      }
      if(got<2) T.check=0;
      rc[2]=solve_dual(cin,4,1u<<2);
      rc[3]=solve_dual(cin,4,1u<<3);
      if(rc[2]==0xFFFFFFFFu||rc[3]==0xFFFFFFFFu) T.check=0;
    }
    // biorthogonality <rc_i, cin_j> = delta
    for(int i=0;i<4;++i)
      for(int j=0;j<4;++j)
        if((u32)(__builtin_popcount(rc[i]&cin[j])&1) != (u32)((i==j)?1:0)) T.check=0;
    // null space of masks (10-dim)
    u32 basis[14]; int nb=nullspace(cin,4,basis);
    if(nb!=10) T.check=0;
    // rows of W: GB rows = roles; bank-bit rows (addr 2..4) greedy for rank-5
    u32 rows[14]; for(int i=0;i<14;++i) rows[i]=0;
    rows[0]=rc[0]; rows[1]=rc[1]; rows[12]=rc[2]; rows[13]=rc[3];
    // lane dims (old addr bits): n -> {2,3,4,5}, q -> {12,13}
    u32 span6[6]={0,0,0,0,0,0};
    auto sig6=[&](u32 v)->u32{ return ((v>>2)&15u) | (((v>>12)&3u)<<4); };
    auto addsig=[&](u32 s)->bool{
      for(int b2=5;b2>=0;--b2){
        if(!((s>>b2)&1u)) continue;
        if(span6[b2]) s^=span6[b2]; else { span6[b2]=s; return true; }
      }
      return false;
    };
    addsig(sig6(rc[0])); addsig(sig6(rc[1]));
    bool used[10]; for(int i=0;i<10;++i) used[i]=false;
    int pick[3]; int np=0;
    for(int i=0;i<10 && np<3;++i)
      if(addsig(sig6(basis[i]))){ pick[np++]=i; used[i]=true; }
    for(int i=0;i<10 && np<3;++i)
      if(!used[i]){ pick[np++]=i; used[i]=true; }
    rows[2]=basis[pick[0]]; rows[3]=basis[pick[1]]; rows[4]=basis[pick[2]];
    int rpos=5;
    for(int i=0;i<10;++i) if(!used[i]) rows[rpos++]=basis[i];
    if(rpos!=12) T.check=0;
    // invertibility of rows
    {
      u32 rr2[14]; for(int i=0;i<14;++i) rr2[i]=rows[i];
      int rank=0;
      for(int i=0;i<14;++i){
        u32 row=rr2[i];
        for(int k=0;k<rank;++k){ int p=top14(rr2[k]); if(p>=0 && ((row>>p)&1u)) row^=rr2[k]; }
        if(row){ rr2[rank]= row; ++rank; }
      }
      // simple re-check via full gaussian
      u32 m2[14]; for(int i=0;i<14;++i) m2[i]=rows[i];
      int rk=0;
      for(int col=13;col>=0;--col){
        int p=-1;
        for(int i=rk;i<14;++i) if((m2[i]>>col)&1u){p=i;break;}
        if(p<0) continue;
        u32 tmp=m2[rk]; m2[rk]=m2[p]; m2[p]=tmp;
        for(int i=0;i<14;++i) if(i!=rk && ((m2[i]>>col)&1u)) m2[i]^=m2[rk];
        ++rk;
      }
      if(rk!=14) T.check=0;
    }
    // columns of W
    Lin W;
    for(int j=0;j<14;++j){ u32 cc=0; for(int i=0;i<14;++i) cc|=((rows[i]>>j)&1u)<<i; W.c[j]=cc; }
    // verify W cin_i = e_GB_i
    for(int i=0;i<4;++i)
      if(lapply(W,cin[i]) != (1u<<GBh[i])) T.check=0;
    if(b==0){
      for(int j=0;j<10;++j) T.a0[j]=W.c[j];
      for(int gm=0;gm<16;++gm){ u32 xx=0; for(int i2=0;i2<4;++i2) if((gm>>i2)&1) xx^=W.c[10+i2]; T.b0[gm]=xx; }
    } else {
      for(int j=0;j<10;++j) T.wC[b-1][j]=W.c[2+j];
      T.wG[b-1][0]=W.c[0]; T.wG[b-1][1]=W.c[1]; T.wG[b-1][2]=W.c[12]; T.wG[b-1][3]=W.c[13];
    }
    S=lcompose(W,S);
    // verify canonical masks AND roles in the new layout
    Lin invS2=linverse(S);
    for(int i=0;i<ng;++i){
      if(lapply(S,MU[layer*NQ+q0+i]) != (1u<<GBh[i])) T.check=0;
      if(roletrans(invS2,RHO[layer*NQ+q0+i]) != (1u<<GBh[i])) T.check=0;
    }
  }
  Lin invF=linverse(S);
  u32 e0=roletrans(invF,er0), e1=roletrans(invF,er1);
  T.erlo[0]=(e0>>2)&0x3FFu;
  T.erhi[0]=(e0&3u)|(((e0>>12)&3u)<<2);
  T.erlo[1]=(e1>>2)&0x3FFu;
  T.erhi[1]=(e1&3u)|(((e1>>12)&3u)<<2);
  return T;
}

} // namespace qct

// ---------------- device code ----------------

// pre-kernel: per-lane MFMA A-fragments (identical to R8 — verified).
__global__ void gate_kernel(const float* __restrict__ wgt, u32* __restrict__ gA){
  __shared__ float us[84][8];
  const int t = threadIdx.x;
  if (t < 84) {
    const float phi=wgt[3*t+0], th=wgt[3*t+1], om=wgt[3*t+2];
    const float ct=cosf(0.5f*th), stt=sinf(0.5f*th);
    const float aa=0.5f*(phi+om), bb=0.5f*(phi-om);
    const float ca=cosf(aa), sa=sinf(aa);
    const float cb=cosf(bb), sb=sinf(bb);
    us[t][0]= ca*ct;  us[t][1]=-sa*ct;
    us[t][2]=-cb*stt; us[t][3]=-sb*stt;
    us[t][4]= cb*stt; us[t][5]=-sb*stt;
    us[t][6]= ca*ct;  us[t][7]= sa*ct;
  }
  __syncthreads();
  for (int task = t; task < NPASS*64; task += (int)blockDim.x) {
    const int p = task >> 6, l = task & 63;
    const int m = l & 15, gb = ((l>>4)&3)*4;
    const int layer = p>>2, g = p&3;
    const int ng = (g<3)?4:2, q0 = (g<3)?4*g:12;
    u32 rre[4], rim[4];
    for (int r = 0; r < 4; ++r) {
      const int gam = gb + r;
      float ure=1.f, uim=0.f; bool zero=false;
      for (int sl = 0; sl < 4; ++sl) {
        const int mb=(m>>sl)&1, cbit=(gam>>sl)&1;
        float fre, fim;
        if (sl < ng) {
          const float* u = us[layer*NQ + q0 + sl];
          fre = u[(mb*2+cbit)*2]; fim = u[(mb*2+cbit)*2+1];
        } else {
          if (mb != cbit) zero = true;
          fre = 1.f; fim = 0.f;
        }
        const float nre = ure*fre - uim*fim;
        const float nim = ure*fim + uim*fre;
        ure = nre; uim = nim;
      }
      if (zero) { ure = 0.f; uim = 0.f; }
      h2v a; a.x=(_Float16)ure;  a.y=(_Float16)(-uim);
      h2v bq; bq.x=(_Float16)uim; bq.y=(_Float16)ure;
      __builtin_memcpy(&rre[r], &a, 4);
      __builtin_memcpy(&rim[r], &bq, 4);
    }
    u32* o0 = gA + ((size_t)(p*2+0)*64 + l)*4;
    u32* o1 = gA + ((size_t)(p*2+1)*64 + l)*4;
    o0[0]=rre[0]; o0[1]=rre[1]; o0[2]=rre[2]; o0[3]=rre[3];
    o1[0]=rim[0]; o1[1]=rim[1]; o1[2]=rim[2]; o1[3]=rim[3];
  }
}

extern "C" __global__ void __launch_bounds__(BLOCK, 8)
qc_kernel(const float* __restrict__ x, const uint4* __restrict__ gA,
          float* __restrict__ out, const AllTables T){
  extern __shared__ u32 lds[];                // 16384 u32 = 64 KiB
  const u32 t = threadIdx.x;
  const u32 s = blockIdx.x;
  const u32 l = t & 63u, w = t >> 6;
  const u32 q = l >> 4, n = l & 15u;

  // --- encoding angles (LDS scratch overlaps state; barrier-ordered) ---
  float* encf = reinterpret_cast<float*>(lds);
  if (t < NQ) {
    const float h = x[s*NQ + t] * 1.57079632679489662f;
    encf[2*t]   = cosf(h);
    encf[2*t+1] = sinf(h);
  }
  __syncthreads();

  // --- init: product state scattered through W_0 ---
  {
    float pr = 1.0f;
    #pragma unroll
    for (int b = 0; b < 10; ++b) pr *= encf[2*(13-b) + ((t>>b)&1u)];
    float e[8];
    #pragma unroll
    for (int j = 0; j < 8; ++j) e[j] = encf[j];
    __syncthreads();
    u32 a0f = 0;
    #pragma unroll
    for (int j = 0; j < 10; ++j) a0f ^= (0u-((t>>j)&1u)) & T.a0[j];
    #pragma unroll
    for (int i = 0; i < 16; ++i) {
      float vv = pr;
      #pragma unroll
      for (int bq = 0; bq < 4; ++bq) vv *= e[2*(3-bq) + ((i>>bq)&1)];
      h2v hv; hv.x = (_Float16)vv; hv.y = (_Float16)0.0f;
      u32 av; __builtin_memcpy(&av, &hv, 4);
      lds[a0f ^ T.b0[i]] = av;
    }
  }
  __syncthreads();

  // static (pass-invariant) read word addresses: one b128 per tile
  u32 rdw[4];
  #pragma unroll
  for (int jt = 0; jt < 4; ++jt) {
    const u32 ci = (w<<6) | ((u32)jt<<4) | n;
    rdw[jt] = (ci<<2) | (q<<12);
  }

  const f4 z = {0.f, 0.f, 0.f, 0.f};

  // --- passes 0..22 (pack + scatter store) ---
  #pragma unroll 1
  for (int k = 0; k < NPASS-1; ++k) {
    const uint4 ar4 = gA[(size_t)(k*2+0)*64 + l];
    const uint4 ai4 = gA[(size_t)(k*2+1)*64 + l];
    h8 aRe, aIm;
    __builtin_memcpy(&aRe, &ar4, 16);
    __builtin_memcpy(&aIm, &ai4, 16);

    uint4 bv0 = *reinterpret_cast<const uint4*>(&lds[rdw[0]]);
    uint4 bv1 = *reinterpret_cast<const uint4*>(&lds[rdw[1]]);
    uint4 bv2 = *reinterpret_cast<const uint4*>(&lds[rdw[2]]);
    uint4 bv3 = *reinterpret_cast<const uint4*>(&lds[rdw[3]]);

    u32 po[4][4];
    {
      uint4 bvv[4] = {bv0, bv1, bv2, bv3};
      #pragma unroll
      for (int jt = 0; jt < 4; ++jt) {
        h8 bf; __builtin_memcpy(&bf, &bvv[jt], 16);
        f4 r1 = __builtin_amdgcn_mfma_f32_16x16x32_f16(aRe, bf, z, 0, 0, 0);
        f4 r2 = __builtin_amdgcn_mfma_f32_16x16x32_f16(aIm, bf, z, 0, 0, 0);
        #pragma unroll
        for (int rr = 0; rr < 4; ++rr) {
          p2v hv = __builtin_amdgcn_cvt_pkrtz(r1[rr], r2[rr]);
          __builtin_memcpy(&po[jt][rr], &hv, 4);
        }
      }
    }

    __syncthreads();   // all reads done before any scatter lands

    u32 bw = 0;
    #pragma unroll
    for (int j = 0; j < 4; ++j) bw ^= (0u-((n>>j)&1u)) & T.wC[k][j];
    #pragma unroll
    for (int j = 0; j < 4; ++j) bw ^= (0u-((w>>j)&1u)) & T.wC[k][6+j];
    bw ^= (0u-(q&1u))      & T.wG[k][2];
    bw ^= (0u-((q>>1)&1u)) & T.wG[k][3];
    const u32 g1 = T.wG[k][0], g2 = T.wG[k][1], g12 = g1^g2;
    #pragma unroll
    for (int jt = 0; jt < 4; ++jt) {
      const u32 ab = bw ^ ((jt&1)?T.wC[k][4]:0u) ^ ((jt&2)?T.wC[k][5]:0u);
      lds[ab]      = po[jt][0];
      lds[ab^g1]   = po[jt][1];
      lds[ab^g2]   = po[jt][2];
      lds[ab^g12]  = po[jt][3];
    }
    __syncthreads();   // scatter complete before next pass reads
  }

  // --- pass 23 fused with expectation (f32 accums, no store) ---
  float z0 = 0.f, z1 = 0.f;
  {
    const int k = NPASS-1;
    const uint4 ar4 = gA[(size_t)(k*2+0)*64 + l];
    const uint4 ai4 = gA[(size_t)(k*2+1)*64 + l];
    h8 aRe, aIm;
    __builtin_memcpy(&aRe, &ar4, 16);
    __builtin_memcpy(&aIm, &ai4, 16);
    const u32 gq0 = (u32)(__popc((q<<2) & T.erhi[0]) & 1);
    const u32 gq1 = (u32)(__popc((q<<2) & T.erhi[1]) & 1);
    #pragma unroll
    for (int jt = 0; jt < 4; ++jt) {
      uint4 bv = *reinterpret_cast<const uint4*>(&lds[rdw[jt]]);
      h8 bf; __builtin_memcpy(&bf, &bv, 16);
      f4 r1 = __builtin_amdgcn_mfma_f32_16x16x32_f16(aRe, bf, z, 0, 0, 0);
      f4 r2 = __builtin_amdgcn_mfma_f32_16x16x32_f16(aIm, bf, z, 0, 0, 0);
      const u32 ci = (w<<6) | ((u32)jt<<4) | n;
      const u32 c0 = (u32)((__popc(ci & T.erlo[0]) & 1) ^ gq0);
      const u32 c1 = (u32)((__popc(ci & T.erlo[1]) & 1) ^ gq1);
      #pragma unroll
      for (int rr = 0; rr < 4; ++rr) {
        const u32 s0 = c0 ^ (u32)(__popc((u32)rr & T.erhi[0]) & 1);
        const u32 s1 = c1 ^ (u32)(__popc((u32)rr & T.erhi[1]) & 1);
        const float p = r1[rr]*r1[rr] + r2[rr]*r2[rr];
        z0 += s0 ? -p : p;
        z1 += s1 ? -p : p;
      }
    }
  }

  #pragma unroll
  for (int off = 32; off > 0; off >>= 1) {
    z0 += __shfl_down(z0, off, 64);
    z1 += __shfl_down(z1, off, 64);
  }
  __syncthreads();                       // state reads finished; reuse LDS
  float* red = reinterpret_cast<float*>(lds);
  if ((t & 63u) == 0u) { red[(t>>6)*2] = z0; red[(t>>6)*2+1] = z1; }
  __syncthreads();
  if (t == 0) {
    float a0s = 0.f, a1s = 0.f;
    #pragma unroll
    for (int kk = 0; kk < 16; ++kk) { a0s += red[2*kk]; a1s += red[2*kk+1]; }
    out[2*s]   = a0s;
    out[2*s+1] = a1s;
  }
}

extern "C" void kernel_launch(void* const* d_in, const int* in_sizes, int n_in,
                              void* d_out, int out_size, void* d_ws, size_t ws_size,
                              hipStream_t stream) {
  const float* x = (const float*)d_in[0];   // (4096, 14) f32
  const float* w = (const float*)d_in[1];   // (6, 14, 3) f32
  float* out = (float*)d_out;               // (4096, 2) f32
  u32* gA = (u32*)d_ws;                     // 24*2*64*4 u32 = 48 KiB
  const int B = in_sizes[0] / NQ;

  const AllTables T = qct::make_all();      // deterministic, no search loops

  gate_kernel<<<1, BLOCK, 0, stream>>>(w, gA);

  const size_t lds_bytes = (size_t)NSTATE * sizeof(u32);   // 65536 B
  (void)hipFuncSetAttribute(reinterpret_cast<const void*>(qc_kernel),
                            hipFuncAttributeMaxDynamicSharedMemorySize,
                            (int)lds_bytes);
  qc_kernel<<<B, BLOCK, lds_bytes, stream>>>(x, (const uint4*)gA, out, T);
}

// Round 10
// 634.692 us; speedup vs baseline: 77.2490x; 1.0029x over previous
//
#include <hip/hip_runtime.h>
#include <string.h>

// Quantum classifier fwd: 14 qubits, batch 4096, 6 StronglyEntanglingLayers.
// Round 10 (= Round 9 + verified bank-rank write maps).
//  - MFMA formulation: pass = 16x16 complex unitary; 2x mfma_f32_16x16x32_f16
//    per 16-col tile; B-frag = packed {re,im} f16 amps straight from LDS b128
//  - roles purged into gamma bits (W rows = role duals) -> static read addrs
//  - write scatter rows[2..4] (bank bits 2..4) chosen by bounded deterministic
//    search maximizing rank of the 5x6 lane->bank GF(2) matrix (verified),
//    fixing R9's silent rank collapse (2.18e8 bank-conflict cycles)

#define NQ     14
#define NL     6
#define NSTATE 16384
#define BLOCK  1024
#define NPASS  24

typedef unsigned u32;
typedef _Float16 h8  __attribute__((ext_vector_type(8)));
typedef _Float16 h2v __attribute__((ext_vector_type(2)));
typedef __fp16   p2v __attribute__((ext_vector_type(2)));
typedef float    f4  __attribute__((ext_vector_type(4)));

struct AllTables {
  u32 wC[NPASS-1][10];  // write map: images of col bits (ci bit j -> addr)
  u32 wG[NPASS-1][4];   // write map: images of gamma bits {0,1,12,13}
  u32 a0[10], b0[16];   // init scatter (= W_0 over original basis)
  u32 erlo[2], erhi[2]; // expectation sign rows (col / gamma spaces)
  int check;
};

// gamma bit i lives at address bit GB[i]; col bit j at addr bit 2+j
static const int GBh[4] = {0, 1, 12, 13};

// ---------------- host-side GF(2) machinery ----------------
namespace qct {

struct GF2 { unsigned short r[NQ]; };
static GF2 gf2_id(){ GF2 m{}; for(int i=0;i<NQ;++i) m.r[i]=(unsigned short)(1u<<i); return m; }
static GF2 gf2_mul(const GF2& A, const GF2& B){
  GF2 C{};
  for(int i=0;i<NQ;++i){ u32 v=0; for(int k=0;k<NQ;++k) if((A.r[i]>>k)&1) v^=B.r[k]; C.r[i]=(unsigned short)v; }
  return C;
}
static GF2 cnotF(int c, int t){
  GF2 F=gf2_id();
  F.r[13-t]=(unsigned short)((1u<<(13-t))|(1u<<(13-c)));
  return F;
}

struct Lin { u32 c[14]; };
static u32 lapply(const Lin& L, u32 x){ u32 r=0; for(int j=0;j<14;++j) if((x>>j)&1u) r^=L.c[j]; return r; }
static Lin lcompose(const Lin& A, const Lin& B){ Lin R{}; for(int j=0;j<14;++j) R.c[j]=lapply(A,B.c[j]); return R; }
static Lin lident(){ Lin L{}; for(int j=0;j<14;++j) L.c[j]=1u<<j; return L; }
static Lin linverse(const Lin& L){
  u32 rows[14]={0}, inv[14]={0};
  for(int i=0;i<14;++i){ u32 r=0; for(int j=0;j<14;++j) r|=((L.c[j]>>i)&1u)<<j; rows[i]=r; inv[i]=1u<<i; }
  for(int col=0; col<14; ++col){
    int piv=-1;
    for(int i=col;i<14;++i) if((rows[i]>>col)&1u){piv=i;break;}
    if(piv<0) continue;
    u32 tr=rows[col]; rows[col]=rows[piv]; rows[piv]=tr;
    tr=inv[col]; inv[col]=inv[piv]; inv[piv]=tr;
    for(int i=0;i<14;++i) if(i!=col && ((rows[i]>>col)&1u)){ rows[i]^=rows[col]; inv[i]^=inv[col]; }
  }
  Lin R{};
  for(int j=0;j<14;++j){ u32 cc=0; for(int i=0;i<14;++i) cc|=((inv[i]>>j)&1u)<<i; R.c[j]=cc; }
  return R;
}
static u32 roletrans(const Lin& invS, u32 rho){
  u32 r=0;
  for(int j=0;j<14;++j) r |= (u32)(__builtin_popcount(invS.c[j]&rho)&1) << j;
  return r;
}

struct Span14 { u32 E[14]; u32 EI[14]; };
static void span_init(Span14& S){ for(int i=0;i<14;++i){S.E[i]=0;S.EI[i]=0;} }
static int top14(u32 v){ for(int i=13;i>=0;--i) if((v>>i)&1u) return i; return -1; }
struct Red { u32 v; u32 img; };
static Red span_reduce(const Span14& S, u32 v){
  u32 img=0;
  while(v){
    int b=top14(v);
    if(!S.E[b]) break;
    v^=S.E[b]; img^=S.EI[b];
  }
  Red r; r.v=v; r.img=img; return r;
}
static bool span_add(Span14& S, u32 v, u32 img){
  Red r=span_reduce(S,v);
  if(!r.v) return false;
  int b=top14(r.v);
  S.E[b]=r.v; S.EI[b]=img^r.img;
  return true;
}

// x with <x, cin[j]> = (tgt>>j)&1 for j<nc; 0xFFFFFFFF on failure
static u32 solve_dual(const u32* cin0, int nc, u32 tgt){
  u32 r[4]; u32 b[4]; int piv[4];
  for(int i=0;i<nc;++i){ r[i]=cin0[i]; b[i]=(tgt>>i)&1u; }
  for(int i=0;i<nc;++i){
    for(int k=0;k<i;++k) if((r[i]>>piv[k])&1u){ r[i]^=r[k]; b[i]^=b[k]; }
    piv[i]=-1;
    for(int p=0;p<14;++p) if((r[i]>>p)&1u){ piv[i]=p; break; }
    if(piv[i]<0) return 0xFFFFFFFFu;
  }
  for(int i=nc-1;i>=0;--i)
    for(int k=0;k<i;++k)
      if((r[k]>>piv[i])&1u){ r[k]^=r[i]; b[k]^=b[i]; }
  u32 x=0;
  for(int i=0;i<nc;++i) if(b[i]) x|=1u<<piv[i];
  return x;
}

// basis of {v : <v,cin_j>=0}; returns count (expect 14-nc)
static int nullspace(const u32* cin0, int nc, u32* basis){
  u32 r[4]; int piv[4]; int rank=0;
  for(int i=0;i<nc;++i){
    u32 row=cin0[i];
    for(int k=0;k<rank;++k) if((row>>piv[k])&1u) row^=r[k];
    if(!row) continue;
    int p=0; while(!((row>>p)&1u)) ++p;
    r[rank]=row; piv[rank]=p; ++rank;
  }
  for(int i=rank-1;i>=0;--i)
    for(int k=0;k<i;++k)
      if((r[k]>>piv[i])&1u) r[k]^=r[i];
  bool isp[14]; for(int i=0;i<14;++i) isp[i]=false;
  for(int i=0;i<rank;++i) isp[piv[i]]=true;
  int nb=0;
  for(int f=0;f<14;++f){
    if(isp[f]) continue;
    u32 v=1u<<f;
    for(int i=0;i<rank;++i) if((r[i]>>f)&1u) v|=1u<<piv[i];
    basis[nb++]=v;
  }
  return nb;
}

// lane-dim signature: addr bits {2,3,4,5} (n) and {12,13} (q)
static u32 sig6(u32 v){ return ((v>>2)&15u) | (((v>>12)&3u)<<4); }

static AllTables make_all(){
  AllTables T; memset(&T,0,sizeof(T)); T.check=1;
  u32 MU[84]={0}, RHO[84]={0}; u32 er0=0, er1=0;
  {
    GF2 G=gf2_id(), H=gf2_id();
    for(int l=0;l<NL;++l){
      for(int q=0;q<NQ;++q){
        int idx=l*NQ+q, bit=13-q;
        u32 m=0;
        for(int r=0;r<NQ;++r) m |= ((u32)((H.r[r]>>bit)&1u))<<r;
        MU[idx]=m; RHO[idx]=G.r[bit];
        if(!(__builtin_popcount(m & (u32)G.r[bit])&1)) T.check=0;
      }
      int rr=(l%(NQ-1))+1;
      GF2 C=gf2_id(), Ci=gf2_id();
      for(int q=0;q<NQ;++q){
        GF2 F=cnotF(q,(q+rr)%NQ);
        C=gf2_mul(C,F); Ci=gf2_mul(F,Ci);
      }
      G=gf2_mul(Ci,G); H=gf2_mul(H,C);
    }
    er0=G.r[13]; er1=G.r[12];
  }
  Lin S=lident();
  for(int b=0;b<NPASS;++b){
    const int layer=b>>2, g=b&3;
    const int ng=(g<3)?4:2, q0=(g<3)?4*g:12;
    Lin invS=linverse(S);
    u32 cin[4]={0,0,0,0}, rc[4]={0,0,0,0};
    for(int i=0;i<ng;++i){
      cin[i]=lapply(S,MU[layer*NQ+q0+i]);
      rc[i]=roletrans(invS,RHO[layer*NQ+q0+i]);
    }
    if(ng==2){
      int got=0;
      for(u32 cs=1; cs<16384u && got<2; ++cs){
        u32 v=(cs*2654435761u)&16383u;
        if(!v) continue;
        if(__builtin_popcount(v&rc[0])&1) continue;
        if(__builtin_popcount(v&rc[1])&1) continue;
        Span14 tmp; span_init(tmp); bool ind=true;
        for(int i=0;i<2+got;++i) if(!span_add(tmp,cin[i],0)) ind=false;
        if(ind && span_add(tmp,v,0)){ cin[2+got]=v; ++got; }
      }
      if(got<2) T.check=0;
      rc[2]=solve_dual(cin,4,1u<<2);
      rc[3]=solve_dual(cin,4,1u<<3);
      if(rc[2]==0xFFFFFFFFu||rc[3]==0xFFFFFFFFu) T.check=0;
    }
    // biorthogonality <rc_i, cin_j> = delta
    for(int i=0;i<4;++i)
      for(int j=0;j<4;++j)
        if((u32)(__builtin_popcount(rc[i]&cin[j])&1) != (u32)((i==j)?1:0)) T.check=0;
    // null space of masks (10-dim)
    u32 basis[14]; int nb=nullspace(cin,4,basis);
    if(nb!=10) T.check=0;

    // ---- rows of W ----
    u32 rows[14]; for(int i=0;i<14;++i) rows[i]=0;
    rows[0]=rc[0]; rows[1]=rc[1]; rows[12]=rc[2]; rows[13]=rc[3];

    // bank-rank maximizing pick of rows[2..4] from the NS (bounded scan):
    // bank matrix rows = sig6(rows[0..4]); want rank 5 over 6 lane dims.
    u32 bspan[6]={0,0,0,0,0,0};
    auto sig_try=[&](u32 sg)->bool{          // peek: would sg increase rank?
      for(int b2=5;b2>=0;--b2){
        if(!((sg>>b2)&1u)) continue;
        if(bspan[b2]) sg^=bspan[b2]; else return true;
      }
      return false;
    };
    auto sig_add=[&](u32 sg)->bool{
      for(int b2=5;b2>=0;--b2){
        if(!((sg>>b2)&1u)) continue;
        if(bspan[b2]) sg^=bspan[b2]; else { bspan[b2]=sg; return true; }
      }
      return false;
    };
    sig_add(sig6(rc[0])); sig_add(sig6(rc[1]));
    u32 picked[3]; int np=0;
    u32 nsred[3]; int nsn=0;                 // reduced NS span of picked
    auto ns_indep=[&](u32 v)->u32{           // returns reduced v (0 = dependent)
      for(int i=0;i<nsn;++i){ int p=top14(nsred[i]); if(p>=0 && ((v>>p)&1u)) v^=nsred[i]; }
      return v;
    };
    for(u32 m=1; m<1024u && np<3; ++m){
      u32 v=0;
      for(int i=0;i<10;++i) if((m>>i)&1u) v^=basis[i];
      if(!v) continue;
      u32 rdc=ns_indep(v);
      if(!rdc) continue;
      if(!sig_try(sig6(v))) continue;
      sig_add(sig6(v));
      picked[np++]=v;
      nsred[nsn++]=rdc;
    }
    for(int i=0;i<10 && np<3;++i){           // fill (no bank gain available)
      u32 rdc=ns_indep(basis[i]);
      if(!rdc) continue;
      picked[np++]=basis[i];
      nsred[nsn++]=rdc;
    }
    if(np<3) T.check=0;
    rows[2]=picked[0]; rows[3]=picked[1]; rows[4]=picked[2];
    // complete rows[5..11] to a full NS basis
    {
      int rpos=5;
      for(int i=0;i<10 && rpos<12;++i){
        u32 rdc=ns_indep(basis[i]);
        if(!rdc) continue;
        rows[rpos++]=basis[i];
        nsred[nsn>2?2:nsn]=rdc;              // keep reducing against all picked
        // proper: append to reduction set
        // (nsred capacity 3 exceeded; do manual reduction set below instead)
        --rpos; break;                       // fall through to full completion
      }
      // full completion with a growing Gaussian set (restart cleanly):
      u32 red[10]; int rn=0;
      auto red_add=[&](u32 v)->bool{
        for(int i=0;i<rn;++i){ int p=top14(red[i]); if(p>=0 && ((v>>p)&1u)) v^=red[i]; }
        if(!v) return false;
        red[rn++]=v; return true;
      };
      red_add(rows[2]); red_add(rows[3]); red_add(rows[4]);
      rpos=5;
      for(int i=0;i<10 && rpos<12;++i)
        if(red_add(basis[i])) rows[rpos++]=basis[i];
      if(rpos!=12) T.check=0;
    }
    // invertibility of rows (full 14x14 Gaussian)
    {
      u32 m2[14]; for(int i=0;i<14;++i) m2[i]=rows[i];
      int rk=0;
      for(int col=13;col>=0;--col){
        int p=-1;
        for(int i=rk;i<14;++i) if((m2[i]>>col)&1u){p=i;break;}
        if(p<0) continue;
        u32 tmp=m2[rk]; m2[rk]=m2[p]; m2[p]=tmp;
        for(int i=0;i<14;++i) if(i!=rk && ((m2[i]>>col)&1u)) m2[i]^=m2[rk];
        ++rk;
      }
      if(rk!=14) T.check=0;
    }
    // columns of W
    Lin W;
    for(int j=0;j<14;++j){ u32 cc=0; for(int i=0;i<14;++i) cc|=((rows[i]>>j)&1u)<<i; W.c[j]=cc; }
    for(int i=0;i<4;++i)
      if(lapply(W,cin[i]) != (1u<<GBh[i])) T.check=0;
    if(b==0){
      for(int j=0;j<10;++j) T.a0[j]=W.c[j];
      for(int gm=0;gm<16;++gm){ u32 xx=0; for(int i2=0;i2<4;++i2) if((gm>>i2)&1) xx^=W.c[10+i2]; T.b0[gm]=xx; }
    } else {
      for(int j=0;j<10;++j) T.wC[b-1][j]=W.c[2+j];
      T.wG[b-1][0]=W.c[0]; T.wG[b-1][1]=W.c[1]; T.wG[b-1][2]=W.c[12]; T.wG[b-1][3]=W.c[13];
    }
    S=lcompose(W,S);
    Lin invS2=linverse(S);
    for(int i=0;i<ng;++i){
      if(lapply(S,MU[layer*NQ+q0+i]) != (1u<<GBh[i])) T.check=0;
      if(roletrans(invS2,RHO[layer*NQ+q0+i]) != (1u<<GBh[i])) T.check=0;
    }
  }
  Lin invF=linverse(S);
  u32 e0=roletrans(invF,er0), e1=roletrans(invF,er1);
  T.erlo[0]=(e0>>2)&0x3FFu;
  T.erhi[0]=(e0&3u)|(((e0>>12)&3u)<<2);
  T.erlo[1]=(e1>>2)&0x3FFu;
  T.erhi[1]=(e1&3u)|(((e1>>12)&3u)<<2);
  return T;
}

} // namespace qct

// ---------------- device code ----------------

// pre-kernel: per-lane MFMA A-fragments (identical to R8/R9 — verified).
__global__ void gate_kernel(const float* __restrict__ wgt, u32* __restrict__ gA){
  __shared__ float us[84][8];
  const int t = threadIdx.x;
  if (t < 84) {
    const float phi=wgt[3*t+0], th=wgt[3*t+1], om=wgt[3*t+2];
    const float ct=cosf(0.5f*th), stt=sinf(0.5f*th);
    const float aa=0.5f*(phi+om), bb=0.5f*(phi-om);
    const float ca=cosf(aa), sa=sinf(aa);
    const float cb=cosf(bb), sb=sinf(bb);
    us[t][0]= ca*ct;  us[t][1]=-sa*ct;
    us[t][2]=-cb*stt; us[t][3]=-sb*stt;
    us[t][4]= cb*stt; us[t][5]=-sb*stt;
    us[t][6]= ca*ct;  us[t][7]= sa*ct;
  }
  __syncthreads();
  for (int task = t; task < NPASS*64; task += (int)blockDim.x) {
    const int p = task >> 6, l = task & 63;
    const int m = l & 15, gb = ((l>>4)&3)*4;
    const int layer = p>>2, g = p&3;
    const int ng = (g<3)?4:2, q0 = (g<3)?4*g:12;
    u32 rre[4], rim[4];
    for (int r = 0; r < 4; ++r) {
      const int gam = gb + r;
      float ure=1.f, uim=0.f; bool zero=false;
      for (int sl = 0; sl < 4; ++sl) {
        const int mb=(m>>sl)&1, cbit=(gam>>sl)&1;
        float fre, fim;
        if (sl < ng) {
          const float* u = us[layer*NQ + q0 + sl];
          fre = u[(mb*2+cbit)*2]; fim = u[(mb*2+cbit)*2+1];
        } else {
          if (mb != cbit) zero = true;
          fre = 1.f; fim = 0.f;
        }
        const float nre = ure*fre - uim*fim;
        const float nim = ure*fim + uim*fre;
        ure = nre; uim = nim;
      }
      if (zero) { ure = 0.f; uim = 0.f; }
      h2v a; a.x=(_Float16)ure;  a.y=(_Float16)(-uim);
      h2v bq; bq.x=(_Float16)uim; bq.y=(_Float16)ure;
      __builtin_memcpy(&rre[r], &a, 4);
      __builtin_memcpy(&rim[r], &bq, 4);
    }
    u32* o0 = gA + ((size_t)(p*2+0)*64 + l)*4;
    u32* o1 = gA + ((size_t)(p*2+1)*64 + l)*4;
    o0[0]=rre[0]; o0[1]=rre[1]; o0[2]=rre[2]; o0[3]=rre[3];
    o1[0]=rim[0]; o1[1]=rim[1]; o1[2]=rim[2]; o1[3]=rim[3];
  }
}

extern "C" __global__ void __launch_bounds__(BLOCK, 8)
qc_kernel(const float* __restrict__ x, const uint4* __restrict__ gA,
          float* __restrict__ out, const AllTables T){
  extern __shared__ u32 lds[];                // 16384 u32 = 64 KiB
  const u32 t = threadIdx.x;
  const u32 s = blockIdx.x;
  const u32 l = t & 63u, w = t >> 6;
  const u32 q = l >> 4, n = l & 15u;

  // --- encoding angles (LDS scratch overlaps state; barrier-ordered) ---
  float* encf = reinterpret_cast<float*>(lds);
  if (t < NQ) {
    const float h = x[s*NQ + t] * 1.57079632679489662f;
    encf[2*t]   = cosf(h);
    encf[2*t+1] = sinf(h);
  }
  __syncthreads();

  // --- init: product state scattered through W_0 ---
  {
    float pr = 1.0f;
    #pragma unroll
    for (int b = 0; b < 10; ++b) pr *= encf[2*(13-b) + ((t>>b)&1u)];
    float e[8];
    #pragma unroll
    for (int j = 0; j < 8; ++j) e[j] = encf[j];
    __syncthreads();
    u32 a0f = 0;
    #pragma unroll
    for (int j = 0; j < 10; ++j) a0f ^= (0u-((t>>j)&1u)) & T.a0[j];
    #pragma unroll
    for (int i = 0; i < 16; ++i) {
      float vv = pr;
      #pragma unroll
      for (int bq = 0; bq < 4; ++bq) vv *= e[2*(3-bq) + ((i>>bq)&1)];
      h2v hv; hv.x = (_Float16)vv; hv.y = (_Float16)0.0f;
      u32 av; __builtin_memcpy(&av, &hv, 4);
      lds[a0f ^ T.b0[i]] = av;
    }
  }
  __syncthreads();

  // static (pass-invariant) read word addresses: one b128 per tile
  u32 rdw[4];
  #pragma unroll
  for (int jt = 0; jt < 4; ++jt) {
    const u32 ci = (w<<6) | ((u32)jt<<4) | n;
    rdw[jt] = (ci<<2) | (q<<12);
  }

  const f4 z = {0.f, 0.f, 0.f, 0.f};

  // --- passes 0..22 (pack + scatter store) ---
  #pragma unroll 1
  for (int k = 0; k < NPASS-1; ++k) {
    const uint4 ar4 = gA[(size_t)(k*2+0)*64 + l];
    const uint4 ai4 = gA[(size_t)(k*2+1)*64 + l];
    h8 aRe, aIm;
    __builtin_memcpy(&aRe, &ar4, 16);
    __builtin_memcpy(&aIm, &ai4, 16);

    uint4 bv0 = *reinterpret_cast<const uint4*>(&lds[rdw[0]]);
    uint4 bv1 = *reinterpret_cast<const uint4*>(&lds[rdw[1]]);
    uint4 bv2 = *reinterpret_cast<const uint4*>(&lds[rdw[2]]);
    uint4 bv3 = *reinterpret_cast<const uint4*>(&lds[rdw[3]]);

    u32 po[4][4];
    {
      uint4 bvv[4] = {bv0, bv1, bv2, bv3};
      #pragma unroll
      for (int jt = 0; jt < 4; ++jt) {
        h8 bf; __builtin_memcpy(&bf, &bvv[jt], 16);
        f4 r1 = __builtin_amdgcn_mfma_f32_16x16x32_f16(aRe, bf, z, 0, 0, 0);
        f4 r2 = __builtin_amdgcn_mfma_f32_16x16x32_f16(aIm, bf, z, 0, 0, 0);
        #pragma unroll
        for (int rr = 0; rr < 4; ++rr) {
          p2v hv = __builtin_amdgcn_cvt_pkrtz(r1[rr], r2[rr]);
          __builtin_memcpy(&po[jt][rr], &hv, 4);
        }
      }
    }

    __syncthreads();   // all reads done before any scatter lands

    u32 bw = 0;
    #pragma unroll
    for (int j = 0; j < 4; ++j) bw ^= (0u-((n>>j)&1u)) & T.wC[k][j];
    #pragma unroll
    for (int j = 0; j < 4; ++j) bw ^= (0u-((w>>j)&1u)) & T.wC[k][6+j];
    bw ^= (0u-(q&1u))      & T.wG[k][2];
    bw ^= (0u-((q>>1)&1u)) & T.wG[k][3];
    const u32 g1 = T.wG[k][0], g2 = T.wG[k][1], g12 = g1^g2;
    #pragma unroll
    for (int jt = 0; jt < 4; ++jt) {
      const u32 ab = bw ^ ((jt&1)?T.wC[k][4]:0u) ^ ((jt&2)?T.wC[k][5]:0u);
      lds[ab]      = po[jt][0];
      lds[ab^g1]   = po[jt][1];
      lds[ab^g2]   = po[jt][2];
      lds[ab^g12]  = po[jt][3];
    }
    __syncthreads();   // scatter complete before next pass reads
  }

  // --- pass 23 fused with expectation (f32 accums, no store) ---
  float z0 = 0.f, z1 = 0.f;
  {
    const int k = NPASS-1;
    const uint4 ar4 = gA[(size_t)(k*2+0)*64 + l];
    const uint4 ai4 = gA[(size_t)(k*2+1)*64 + l];
    h8 aRe, aIm;
    __builtin_memcpy(&aRe, &ar4, 16);
    __builtin_memcpy(&aIm, &ai4, 16);
    const u32 gq0 = (u32)(__popc((q<<2) & T.erhi[0]) & 1);
    const u32 gq1 = (u32)(__popc((q<<2) & T.erhi[1]) & 1);
    #pragma unroll
    for (int jt = 0; jt < 4; ++jt) {
      uint4 bv = *reinterpret_cast<const uint4*>(&lds[rdw[jt]]);
      h8 bf; __builtin_memcpy(&bf, &bv, 16);
      f4 r1 = __builtin_amdgcn_mfma_f32_16x16x32_f16(aRe, bf, z, 0, 0, 0);
      f4 r2 = __builtin_amdgcn_mfma_f32_16x16x32_f16(aIm, bf, z, 0, 0, 0);
      const u32 ci = (w<<6) | ((u32)jt<<4) | n;
      const u32 c0 = (u32)((__popc(ci & T.erlo[0]) & 1) ^ gq0);
      const u32 c1 = (u32)((__popc(ci & T.erlo[1]) & 1) ^ gq1);
      #pragma unroll
      for (int rr = 0; rr < 4; ++rr) {
        const u32 s0 = c0 ^ (u32)(__popc((u32)rr & T.erhi[0]) & 1);
        const u32 s1 = c1 ^ (u32)(__popc((u32)rr & T.erhi[1]) & 1);
        const float p = r1[rr]*r1[rr] + r2[rr]*r2[rr];
        z0 += s0 ? -p : p;
        z1 += s1 ? -p : p;
      }
    }
  }

  #pragma unroll
  for (int off = 32; off > 0; off >>= 1) {
    z0 += __shfl_down(z0, off, 64);
    z1 += __shfl_down(z1, off, 64);
  }
  __syncthreads();                       // state reads finished; reuse LDS
  float* red = reinterpret_cast<float*>(lds);
  if ((t & 63u) == 0u) { red[(t>>6)*2] = z0; red[(t>>6)*2+1] = z1; }
  __syncthreads();
  if (t == 0) {
    float a0s = 0.f, a1s = 0.f;
    #pragma unroll
    for (int kk = 0; kk < 16; ++kk) { a0s += red[2*kk]; a1s += red[2*kk+1]; }
    out[2*s]   = a0s;
    out[2*s+1] = a1s;
  }
}

extern "C" void kernel_launch(void* const* d_in, const int* in_sizes, int n_in,
                              void* d_out, int out_size, void* d_ws, size_t ws_size,
                              hipStream_t stream) {
  const float* x = (const float*)d_in[0];   // (4096, 14) f32
  const float* w = (const float*)d_in[1];   // (6, 14, 3) f32
  float* out = (float*)d_out;               // (4096, 2) f32
  u32* gA = (u32*)d_ws;                     // 24*2*64*4 u32 = 48 KiB
  const int B = in_sizes[0] / NQ;

  const AllTables T = qct::make_all();      // deterministic, bounded, ~0.1 ms

  gate_kernel<<<1, BLOCK, 0, stream>>>(w, gA);

  const size_t lds_bytes = (size_t)NSTATE * sizeof(u32);   // 65536 B
  (void)hipFuncSetAttribute(reinterpret_cast<const void*>(qc_kernel),
                            hipFuncAttributeMaxDynamicSharedMemorySize,
                            (int)lds_bytes);
  qc_kernel<<<B, BLOCK, lds_bytes, stream>>>(x, (const uint4*)gA, out, T);
}